// Round 2
// baseline (1644.160 us; speedup 1.0000x reference)
//
#include <hip/hip_runtime.h>
#include <hip/hip_bf16.h>

#define FDIM 128

__device__ __forceinline__ float sp(float x) {
    // softplus = log(1+exp(x)), numerically stable (== jnp.logaddexp(x,0))
    return fmaxf(x, 0.0f) + log1pf(expf(-fabsf(x)));
}

// Y[r][:] = POST( PRE(X[r][:]) @ W + bias ) (+ residual)
// PRE : 0 = identity, 1 = softplus
// POST: 0 = none, 1 = softplus, 2 = softplus(softplus(.))
// RES : 0 = none, 1 = + resid[r][c], 2 = + gate[c]*resid[r][c]
template<int PRE, int POST, int RES>
__global__ __launch_bounds__(256) void gemm_f32(
    const float* __restrict__ X, const float* __restrict__ W,
    const float* __restrict__ bias, const float* __restrict__ resid,
    const float* __restrict__ gate, float* __restrict__ Y, int nrows)
{
    __shared__ float Ws[64 * FDIM];  // 32 KB: K-half of W, [64][128]
    __shared__ float Xs[64 * 64];    // 16 KB: 64 rows x 64 k, PRE applied

    const int t     = threadIdx.x;
    const int cg    = t & 31;   // column group: cols 4cg..4cg+3
    const int rbase = t >> 5;   // 0..7 (actually 0..1 within wave, 0..7 across block)
    const int row0  = blockIdx.x * 64;

    float4 acc[8];
#pragma unroll
    for (int i = 0; i < 8; ++i) acc[i] = make_float4(0.f, 0.f, 0.f, 0.f);

    for (int kh = 0; kh < 2; ++kh) {
        __syncthreads();  // protect previous half's reads before overwrite
        // stage W[kh*64 .. kh*64+63][0..127]
        {
            const float4* Wg4 = (const float4*)(W + (size_t)kh * 64 * FDIM);
            float4* Ws4 = (float4*)Ws;
#pragma unroll
            for (int i = 0; i < 8; ++i) Ws4[t + 256 * i] = Wg4[t + 256 * i];
        }
        // stage X[row0..row0+63][kh*64 .. kh*64+63], applying PRE
        {
#pragma unroll
            for (int i = 0; i < 4; ++i) {
                int idx = t + 256 * i;       // 0..1023 float4 slots
                int r   = idx >> 4;          // 16 float4 per row
                int c4  = (idx & 15) * 4;
                int gr  = row0 + r;
                float4 v = make_float4(0.f, 0.f, 0.f, 0.f);
                if (gr < nrows)
                    v = *(const float4*)(X + (size_t)gr * FDIM + kh * 64 + c4);
                if (PRE == 1) { v.x = sp(v.x); v.y = sp(v.y); v.z = sp(v.z); v.w = sp(v.w); }
                *(float4*)(Xs + r * 64 + c4) = v;
            }
        }
        __syncthreads();

        const float4* Ws4 = (const float4*)Ws;
#pragma unroll
        for (int k = 0; k < 64; k += 4) {
            float4 w0 = Ws4[(k + 0) * 32 + cg];
            float4 w1 = Ws4[(k + 1) * 32 + cg];
            float4 w2 = Ws4[(k + 2) * 32 + cg];
            float4 w3 = Ws4[(k + 3) * 32 + cg];
#pragma unroll
            for (int pass = 0; pass < 8; ++pass) {
                float4 xv = *(const float4*)(Xs + (pass * 8 + rbase) * 64 + k);
                acc[pass].x += xv.x * w0.x + xv.y * w1.x + xv.z * w2.x + xv.w * w3.x;
                acc[pass].y += xv.x * w0.y + xv.y * w1.y + xv.z * w2.y + xv.w * w3.y;
                acc[pass].z += xv.x * w0.z + xv.y * w1.z + xv.z * w2.z + xv.w * w3.z;
                acc[pass].w += xv.x * w0.w + xv.y * w1.w + xv.z * w2.w + xv.w * w3.w;
            }
        }
    }

    // epilogue
    float4 b4 = *(const float4*)(bias + cg * 4);
#pragma unroll
    for (int pass = 0; pass < 8; ++pass) {
        int gr = row0 + pass * 8 + rbase;
        if (gr >= nrows) continue;
        float4 o = acc[pass];
        o.x += b4.x; o.y += b4.y; o.z += b4.z; o.w += b4.w;
        if (POST >= 1) { o.x = sp(o.x); o.y = sp(o.y); o.z = sp(o.z); o.w = sp(o.w); }
        if (POST == 2) { o.x = sp(o.x); o.y = sp(o.y); o.z = sp(o.z); o.w = sp(o.w); }
        if (RES == 1) {
            float4 rv = *(const float4*)(resid + (size_t)gr * FDIM + cg * 4);
            o.x += rv.x; o.y += rv.y; o.z += rv.z; o.w += rv.w;
        }
        if (RES == 2) {
            float4 rv = *(const float4*)(resid + (size_t)gr * FDIM + cg * 4);
            float4 g4 = *(const float4*)(gate + cg * 4);
            o.x += g4.x * rv.x; o.y += g4.y * rv.y; o.z += g4.z * rv.z; o.w += g4.w * rv.w;
        }
        *(float4*)(Y + (size_t)gr * FDIM + cg * 4) = o;
    }
}

// ---- CSR build: histogram -> prefix scan -> bucket fill -------------------

__global__ __launch_bounds__(256) void hist_counts(
    const int* __restrict__ idx_i, int* __restrict__ counts, int npairs)
{
    int p = blockIdx.x * 256 + threadIdx.x;
    if (p < npairs) atomicAdd(&counts[idx_i[p]], 1);
}

// single workgroup of 1024 threads: chunked serial sum + Hillis-Steele scan
__global__ __launch_bounds__(1024) void scan_counts(
    const int* __restrict__ counts, int* __restrict__ offsets,
    int* __restrict__ cursor, int n)
{
    __shared__ int part[1024];
    const int t = threadIdx.x;
    const int chunk = (n + 1023) >> 10;
    int beg = t * chunk; if (beg > n) beg = n;
    int end = beg + chunk; if (end > n) end = n;
    int s = 0;
    for (int i = beg; i < end; ++i) s += counts[i];
    part[t] = s;
    __syncthreads();
    for (int off = 1; off < 1024; off <<= 1) {
        int add = (t >= off) ? part[t - off] : 0;
        __syncthreads();
        part[t] += add;
        __syncthreads();
    }
    int run = (t == 0) ? 0 : part[t - 1];
    for (int i = beg; i < end; ++i) {
        offsets[i] = run;
        cursor[i]  = run;
        run += counts[i];
    }
    if (t == 1023) offsets[n] = run;   // total == npairs
}

__global__ __launch_bounds__(256) void fill_buckets(
    const int* __restrict__ idx_i, int* __restrict__ cursor,
    int* __restrict__ bucket, int npairs)
{
    int p = blockIdx.x * 256 + threadIdx.x;
    if (p >= npairs) return;
    int pos = atomicAdd(&cursor[idx_i[p]], 1);
    bucket[pos] = p;
}

// One wave per atom: xi[i] += sum_{p in bucket(i)} (f_ij[p] @ Wg) * xj[idx_j[p]]
// Wg hoisted into 32 regs/lane; f_ij row read as 4 broadcast float4 loads;
// no atomics (a single wave owns atom i).
__global__ __launch_bounds__(256) void pair_gather(
    const float* __restrict__ f_ij, const int* __restrict__ idx_j,
    const int* __restrict__ bucket, const int* __restrict__ offsets,
    const float* __restrict__ Wg, const float* __restrict__ xj,
    float* __restrict__ xi, int natoms)
{
    const int lane = threadIdx.x & 63;
    const int atom = blockIdx.x * 4 + (threadIdx.x >> 6);
    if (atom >= natoms) return;

    float2 wreg[16];
#pragma unroll
    for (int r = 0; r < 16; ++r)
        wreg[r] = *(const float2*)(Wg + r * FDIM + lane * 2);

    const int beg = offsets[atom], end = offsets[atom + 1];
    float a0 = 0.f, a1 = 0.f;
    for (int q = beg; q < end; ++q) {
        const int p  = bucket[q];
        const int aj = idx_j[p];
        const float4* fp = (const float4*)(f_ij + (size_t)p * 16);
        float4 f0 = fp[0], f1 = fp[1], f2 = fp[2], f3 = fp[3];
        float2 xv = *(const float2*)(xj + (size_t)aj * FDIM + lane * 2);
        float g0 =
            f0.x * wreg[0].x  + f0.y * wreg[1].x  + f0.z * wreg[2].x  + f0.w * wreg[3].x  +
            f1.x * wreg[4].x  + f1.y * wreg[5].x  + f1.z * wreg[6].x  + f1.w * wreg[7].x  +
            f2.x * wreg[8].x  + f2.y * wreg[9].x  + f2.z * wreg[10].x + f2.w * wreg[11].x +
            f3.x * wreg[12].x + f3.y * wreg[13].x + f3.z * wreg[14].x + f3.w * wreg[15].x;
        float g1 =
            f0.x * wreg[0].y  + f0.y * wreg[1].y  + f0.z * wreg[2].y  + f0.w * wreg[3].y  +
            f1.x * wreg[4].y  + f1.y * wreg[5].y  + f1.z * wreg[6].y  + f1.w * wreg[7].y  +
            f2.x * wreg[8].y  + f2.y * wreg[9].y  + f2.z * wreg[10].y + f2.w * wreg[11].y +
            f3.x * wreg[12].y + f3.y * wreg[13].y + f3.z * wreg[14].y + f3.w * wreg[15].y;
        a0 += g0 * xv.x;
        a1 += g1 * xv.y;
    }

    float2* dst = (float2*)(xi + (size_t)atom * FDIM + lane * 2);
    float2 cur = *dst;
    cur.x += a0; cur.y += a1;
    *dst = cur;
}

// prediction[r][0..1] = y[r][:] @ Wout + bout ; one wave per row
__global__ __launch_bounds__(256) void out_proj(
    const float* __restrict__ y, const float* __restrict__ Wout,
    const float* __restrict__ bout, float* __restrict__ pred, int nrows)
{
    const int lane = threadIdx.x & 63;
    const int r = blockIdx.x * 4 + (threadIdx.x >> 6);
    if (r >= nrows) return;

    float v0 = y[(size_t)r * FDIM + lane];
    float v1 = y[(size_t)r * FDIM + 64 + lane];
    float2 w0 = ((const float2*)Wout)[lane];
    float2 w1 = ((const float2*)Wout)[lane + 64];
    float a = v0 * w0.x + v1 * w1.x;
    float b = v0 * w0.y + v1 * w1.y;
#pragma unroll
    for (int o = 32; o > 0; o >>= 1) {
        a += __shfl_down(a, o, 64);
        b += __shfl_down(b, o, 64);
    }
    if (lane == 0) {
        pred[(size_t)r * 2 + 0] = a + bout[0];
        pred[(size_t)r * 2 + 1] = b + bout[1];
    }
}

extern "C" void kernel_launch(void* const* d_in, const int* in_sizes, int n_in,
                              void* d_out, int out_size, void* d_ws, size_t ws_size,
                              hipStream_t stream)
{
    const float* emb     = (const float*)d_in[0];
    const float* f_ij    = (const float*)d_in[1];
    const int*   idx_i   = (const int*)d_in[2];
    const int*   idx_j   = (const int*)d_in[3];
    const float* Wi      = (const float*)d_in[4];
    const float* bi      = (const float*)d_in[5];
    const float* Wj      = (const float*)d_in[6];
    const float* bj      = (const float*)d_in[7];
    const float* Wg      = (const float*)d_in[8];
    const float* Wv      = (const float*)d_in[9];
    const float* bv      = (const float*)d_in[10];
    const float* gate    = (const float*)d_in[11];
    const float* res_w1  = (const float*)d_in[12];
    const float* res_b1  = (const float*)d_in[13];
    const float* res_w2  = (const float*)d_in[14];
    const float* res_b2  = (const float*)d_in[15];
    const float* ores_w1 = (const float*)d_in[16];
    const float* ores_b1 = (const float*)d_in[17];
    const float* ores_w2 = (const float*)d_in[18];
    const float* ores_b2 = (const float*)d_in[19];
    const float* Wout    = (const float*)d_in[20];
    const float* bout    = (const float*)d_in[21];

    const int N = in_sizes[0] / FDIM;   // 50000
    const int P = in_sizes[2];          // 800000

    // workspace layout (all rewritten every call; no cross-call state)
    float* xi   = (float*)d_ws;                         // [N,128]
    float* buf  = xi + (size_t)N * FDIM;                // [N,128] shared: xj -> h -> y
    int*   counts  = (int*)(buf + (size_t)N * FDIM);    // [N]
    int*   offsets = counts + N;                        // [N+1]
    int*   cursor  = offsets + N + 1;                   // [N]
    int*   bucket  = cursor + N;                        // [P]
    float* xj   = buf;
    float* h    = buf;   // alive only after xj dead (post pair_gather)
    float* y    = buf;   // X==Y aliasing safe: blocks touch disjoint row ranges
    float* pred    = (float*)d_out;                     // [N,2]
    float* updated = (float*)d_out + (size_t)N * 2;     // [N,128]

    const dim3 blk(256);
    const int ggrid = (N + 63) / 64;
    const int pgrid = (P + 255) / 256;

    // CSR build for the scatter (int atomics only)
    hipMemsetAsync(counts, 0, (size_t)N * sizeof(int), stream);
    hist_counts<<<pgrid, blk, 0, stream>>>(idx_i, counts, P);
    scan_counts<<<1, 1024, 0, stream>>>(counts, offsets, cursor, N);
    fill_buckets<<<pgrid, blk, 0, stream>>>(idx_i, cursor, bucket, P);

    // xi = act(act(emb @ Wi + bi)); xj = act(act(emb @ Wj + bj))
    gemm_f32<0, 2, 0><<<ggrid, blk, 0, stream>>>(emb, Wi, bi, nullptr, nullptr, xi, N);
    gemm_f32<0, 2, 0><<<ggrid, blk, 0, stream>>>(emb, Wj, bj, nullptr, nullptr, xj, N);

    // xi[i] += sum over pairs of (f_ij @ Wg) * xj[idx_j]  (gather form, no atomics)
    pair_gather<<<(N + 3) / 4, blk, 0, stream>>>(f_ij, idx_j, bucket, offsets,
                                                 Wg, xj, xi, N);

    // 3 residual blocks: xi = xi + act(act(xi)@w1+b1)@w2 + b2
    for (int k = 0; k < 3; ++k) {
        gemm_f32<1, 1, 0><<<ggrid, blk, 0, stream>>>(
            xi, res_w1 + (size_t)k * FDIM * FDIM, res_b1 + (size_t)k * FDIM,
            nullptr, nullptr, h, N);
        gemm_f32<0, 0, 1><<<ggrid, blk, 0, stream>>>(
            h, res_w2 + (size_t)k * FDIM * FDIM, res_b2 + (size_t)k * FDIM,
            xi, nullptr, xi, N);
    }

    // updated = gate*emb + act(xi)@Wv + bv   (written straight to d_out)
    gemm_f32<1, 0, 2><<<ggrid, blk, 0, stream>>>(xi, Wv, bv, emb, gate, updated, N);

    // output residual block on updated -> y
    gemm_f32<1, 1, 0><<<ggrid, blk, 0, stream>>>(updated, ores_w1, ores_b1,
                                                 nullptr, nullptr, h, N);
    gemm_f32<0, 0, 1><<<ggrid, blk, 0, stream>>>(h, ores_w2, ores_b2,
                                                 updated, nullptr, y, N);

    // prediction = y @ Wout + bout
    out_proj<<<(N + 3) / 4, blk, 0, stream>>>(y, Wout, bout, pred, N);
}

// Round 3
// 945.607 us; speedup vs baseline: 1.7387x; 1.7387x over previous
//
#include <hip/hip_runtime.h>
#include <hip/hip_bf16.h>

#define FDIM 128

typedef __attribute__((ext_vector_type(8))) short bf16x8;
typedef __attribute__((ext_vector_type(4))) float f32x4;

__device__ __forceinline__ float sp(float x) {
    // softplus = log(1+exp(x)), numerically stable (== jnp.logaddexp(x,0))
    return fmaxf(x, 0.0f) + log1pf(expf(-fabsf(x)));
}

__device__ __forceinline__ unsigned short bfb(float x) {
    // f32 -> bf16 round-to-nearest-even (inputs are finite; no NaN handling)
    unsigned int u = __float_as_uint(x);
    u += 0x7FFFu + ((u >> 16) & 1u);
    return (unsigned short)(u >> 16);
}

// Y[r][:] = POST( PRE(X[r][:]) @ W + bias ) (+ residual), K = N = 128.
// bf16 MFMA 16x16x32, f32 accumulate. W transposed into LDS (swizzled bf16);
// A-fragments straight from global (each X row read exactly once).
// PRE : 0 = identity, 1 = softplus
// POST: 0 = none, 1 = softplus, 2 = softplus(softplus(.))
// RES : 0 = none, 1 = + resid[r][c], 2 = + gate[c]*resid[r][c]
template<int PRE, int POST, int RES>
__global__ __launch_bounds__(256) void gemm_mfma(
    const float* __restrict__ X, const float* __restrict__ W,
    const float* __restrict__ bias, const float* __restrict__ resid,
    const float* __restrict__ gate, float* __restrict__ Y, int nrows)
{
    __shared__ short Wt[FDIM * FDIM];  // 32 KB: Wt[n][k] bf16, XOR-swizzled

    const int t    = threadIdx.x;
    const int lane = t & 63;
    const int wave = t >> 6;

    // ---- stage W^T into LDS as bf16 (2048 units of 2k x 4n) ----
#pragma unroll
    for (int i = 0; i < 8; ++i) {
        int e  = t + 256 * i;
        int k  = (e >> 5) * 2;
        int n4 = (e & 31) * 4;
        float4 a = *(const float4*)(W + (size_t)k * FDIM + n4);
        float4 b = *(const float4*)(W + (size_t)(k + 1) * FDIM + n4);
        float av[4] = {a.x, a.y, a.z, a.w};
        float bv[4] = {b.x, b.y, b.z, b.w};
#pragma unroll
        for (int j = 0; j < 4; ++j) {
            int n = n4 + j;
            unsigned int pk = (unsigned int)bfb(av[j]) |
                              ((unsigned int)bfb(bv[j]) << 16);
            int byte = n * 256 + k * 2;
            byte ^= (n & 7) << 4;              // bank-conflict swizzle
            *(unsigned int*)((char*)Wt + byte) = pk;
        }
    }

    // ---- A-fragments from global: row = base + (lane&15), k-chunk by lane>>4
    const int row = blockIdx.x * 64 + wave * 16 + (lane & 15);
    const int kc  = (lane >> 4) * 8;
    const bool rowok = row < nrows;

    bf16x8 afr[4];
#pragma unroll
    for (int ks = 0; ks < 4; ++ks) {
        float4 a = make_float4(0.f, 0.f, 0.f, 0.f);
        float4 b = make_float4(0.f, 0.f, 0.f, 0.f);
        if (rowok) {
            const float* xp = X + (size_t)row * FDIM + ks * 32 + kc;
            a = *(const float4*)xp;
            b = *(const float4*)(xp + 4);
        }
        if (PRE == 1) {
            a.x = sp(a.x); a.y = sp(a.y); a.z = sp(a.z); a.w = sp(a.w);
            b.x = sp(b.x); b.y = sp(b.y); b.z = sp(b.z); b.w = sp(b.w);
        }
        bf16x8 f;
        f[0] = (short)bfb(a.x); f[1] = (short)bfb(a.y);
        f[2] = (short)bfb(a.z); f[3] = (short)bfb(a.w);
        f[4] = (short)bfb(b.x); f[5] = (short)bfb(b.y);
        f[6] = (short)bfb(b.z); f[7] = (short)bfb(b.w);
        afr[ks] = f;
    }

    __syncthreads();

    // ---- MFMA K-loop: 4 k-steps x 8 n-tiles ----
    f32x4 acc[8];
#pragma unroll
    for (int n = 0; n < 8; ++n) acc[n] = (f32x4){0.f, 0.f, 0.f, 0.f};

#pragma unroll
    for (int ks = 0; ks < 4; ++ks) {
#pragma unroll
        for (int n = 0; n < 8; ++n) {
            int nn = n * 16 + (lane & 15);
            int byte = nn * 256 + (ks * 32 + kc) * 2;
            byte ^= (nn & 7) << 4;
            bf16x8 bfr = *(const bf16x8*)((const char*)Wt + byte);
            acc[n] = __builtin_amdgcn_mfma_f32_16x16x32_bf16(afr[ks], bfr, acc[n], 0, 0, 0);
        }
    }

    // ---- epilogue: C/D layout col = lane&15, row = (lane>>4)*4 + i ----
    const int rb = blockIdx.x * 64 + wave * 16 + (lane >> 4) * 4;
#pragma unroll
    for (int n = 0; n < 8; ++n) {
        int col = n * 16 + (lane & 15);
        float bcol = bias[col];
        float gcol = (RES == 2) ? gate[col] : 0.f;
#pragma unroll
        for (int i = 0; i < 4; ++i) {
            int gr = rb + i;
            if (gr >= nrows) continue;
            float o = acc[n][i] + bcol;
            if (POST >= 1) o = sp(o);
            if (POST == 2) o = sp(o);
            if (RES == 1) o += resid[(size_t)gr * FDIM + col];
            if (RES == 2) o = fmaf(gcol, resid[(size_t)gr * FDIM + col], o);
            Y[(size_t)gr * FDIM + col] = o;
        }
    }
}

// ---- CSR build: histogram -> prefix scan -> bucket fill -------------------

__global__ __launch_bounds__(256) void hist_counts(
    const int* __restrict__ idx_i, int* __restrict__ counts, int npairs)
{
    int p = blockIdx.x * 256 + threadIdx.x;
    if (p < npairs) atomicAdd(&counts[idx_i[p]], 1);
}

// single workgroup of 1024 threads: chunked serial sum + Hillis-Steele scan
__global__ __launch_bounds__(1024) void scan_counts(
    const int* __restrict__ counts, int* __restrict__ offsets,
    int* __restrict__ cursor, int n)
{
    __shared__ int part[1024];
    const int t = threadIdx.x;
    const int chunk = (n + 1023) >> 10;
    int beg = t * chunk; if (beg > n) beg = n;
    int end = beg + chunk; if (end > n) end = n;
    int s = 0;
    for (int i = beg; i < end; ++i) s += counts[i];
    part[t] = s;
    __syncthreads();
    for (int off = 1; off < 1024; off <<= 1) {
        int add = (t >= off) ? part[t - off] : 0;
        __syncthreads();
        part[t] += add;
        __syncthreads();
    }
    int run = (t == 0) ? 0 : part[t - 1];
    for (int i = beg; i < end; ++i) {
        offsets[i] = run;
        cursor[i]  = run;
        run += counts[i];
    }
    if (t == 1023) offsets[n] = run;   // total == npairs
}

__global__ __launch_bounds__(256) void fill_buckets(
    const int* __restrict__ idx_i, int* __restrict__ cursor,
    int* __restrict__ bucket, int npairs)
{
    int p = blockIdx.x * 256 + threadIdx.x;
    if (p >= npairs) return;
    int pos = atomicAdd(&cursor[idx_i[p]], 1);
    bucket[pos] = p;
}

// One BLOCK per atom: 4 waves split the bucket, combine in LDS, no global
// atomics. xi[i] += sum_{p in bucket(i)} (f_ij[p] @ Wg) * xj[idx_j[p]]
__global__ __launch_bounds__(256) void pair_gather_blk(
    const float* __restrict__ f_ij, const int* __restrict__ idx_j,
    const int* __restrict__ bucket, const int* __restrict__ offsets,
    const float* __restrict__ Wg, const float* __restrict__ xj,
    float* __restrict__ xi, int natoms)
{
    __shared__ float accs[FDIM];
    const int t    = threadIdx.x;
    const int lane = t & 63;
    const int wave = t >> 6;
    const int atom = blockIdx.x;
    if (atom >= natoms) return;

    if (t < FDIM) accs[t] = 0.f;

    float2 wreg[16];
#pragma unroll
    for (int r = 0; r < 16; ++r)
        wreg[r] = *(const float2*)(Wg + r * FDIM + lane * 2);

    __syncthreads();

    const int beg = offsets[atom], end = offsets[atom + 1];
    float a0 = 0.f, a1 = 0.f;
    for (int q = beg + wave; q < end; q += 4) {
        const int p  = bucket[q];
        const int aj = idx_j[p];
        const float4* fp = (const float4*)(f_ij + (size_t)p * 16);
        float4 f0 = fp[0], f1 = fp[1], f2 = fp[2], f3 = fp[3];
        float2 xv = *(const float2*)(xj + (size_t)aj * FDIM + lane * 2);
        float g0 =
            f0.x * wreg[0].x  + f0.y * wreg[1].x  + f0.z * wreg[2].x  + f0.w * wreg[3].x  +
            f1.x * wreg[4].x  + f1.y * wreg[5].x  + f1.z * wreg[6].x  + f1.w * wreg[7].x  +
            f2.x * wreg[8].x  + f2.y * wreg[9].x  + f2.z * wreg[10].x + f2.w * wreg[11].x +
            f3.x * wreg[12].x + f3.y * wreg[13].x + f3.z * wreg[14].x + f3.w * wreg[15].x;
        float g1 =
            f0.x * wreg[0].y  + f0.y * wreg[1].y  + f0.z * wreg[2].y  + f0.w * wreg[3].y  +
            f1.x * wreg[4].y  + f1.y * wreg[5].y  + f1.z * wreg[6].y  + f1.w * wreg[7].y  +
            f2.x * wreg[8].y  + f2.y * wreg[9].y  + f2.z * wreg[10].y + f2.w * wreg[11].y +
            f3.x * wreg[12].y + f3.y * wreg[13].y + f3.z * wreg[14].y + f3.w * wreg[15].y;
        a0 += g0 * xv.x;
        a1 += g1 * xv.y;
    }
    atomicAdd(&accs[lane * 2 + 0], a0);   // LDS ds_add_f32, 4-way max
    atomicAdd(&accs[lane * 2 + 1], a1);
    __syncthreads();
    if (t < FDIM) xi[(size_t)atom * FDIM + t] += accs[t];
}

// prediction[r][0..1] = y[r][:] @ Wout + bout ; one wave per row
__global__ __launch_bounds__(256) void out_proj(
    const float* __restrict__ y, const float* __restrict__ Wout,
    const float* __restrict__ bout, float* __restrict__ pred, int nrows)
{
    const int lane = threadIdx.x & 63;
    const int r = blockIdx.x * 4 + (threadIdx.x >> 6);
    if (r >= nrows) return;

    float v0 = y[(size_t)r * FDIM + lane];
    float v1 = y[(size_t)r * FDIM + 64 + lane];
    float2 w0 = ((const float2*)Wout)[lane];
    float2 w1 = ((const float2*)Wout)[lane + 64];
    float a = v0 * w0.x + v1 * w1.x;
    float b = v0 * w0.y + v1 * w1.y;
#pragma unroll
    for (int o = 32; o > 0; o >>= 1) {
        a += __shfl_down(a, o, 64);
        b += __shfl_down(b, o, 64);
    }
    if (lane == 0) {
        pred[(size_t)r * 2 + 0] = a + bout[0];
        pred[(size_t)r * 2 + 1] = b + bout[1];
    }
}

extern "C" void kernel_launch(void* const* d_in, const int* in_sizes, int n_in,
                              void* d_out, int out_size, void* d_ws, size_t ws_size,
                              hipStream_t stream)
{
    const float* emb     = (const float*)d_in[0];
    const float* f_ij    = (const float*)d_in[1];
    const int*   idx_i   = (const int*)d_in[2];
    const int*   idx_j   = (const int*)d_in[3];
    const float* Wi      = (const float*)d_in[4];
    const float* bi      = (const float*)d_in[5];
    const float* Wj      = (const float*)d_in[6];
    const float* bj      = (const float*)d_in[7];
    const float* Wg      = (const float*)d_in[8];
    const float* Wv      = (const float*)d_in[9];
    const float* bv      = (const float*)d_in[10];
    const float* gate    = (const float*)d_in[11];
    const float* res_w1  = (const float*)d_in[12];
    const float* res_b1  = (const float*)d_in[13];
    const float* res_w2  = (const float*)d_in[14];
    const float* res_b2  = (const float*)d_in[15];
    const float* ores_w1 = (const float*)d_in[16];
    const float* ores_b1 = (const float*)d_in[17];
    const float* ores_w2 = (const float*)d_in[18];
    const float* ores_b2 = (const float*)d_in[19];
    const float* Wout    = (const float*)d_in[20];
    const float* bout    = (const float*)d_in[21];

    const int N = in_sizes[0] / FDIM;   // 50000
    const int P = in_sizes[2];          // 800000

    // workspace layout (all rewritten every call; no cross-call state)
    float* xi   = (float*)d_ws;                         // [N,128]
    float* buf  = xi + (size_t)N * FDIM;                // [N,128] shared: xj -> h -> y
    int*   counts  = (int*)(buf + (size_t)N * FDIM);    // [N]
    int*   offsets = counts + N;                        // [N+1]
    int*   cursor  = offsets + N + 1;                   // [N]
    int*   bucket  = cursor + N;                        // [P]
    float* xj   = buf;
    float* h    = buf;   // alive only after xj dead (post pair_gather_blk)
    float* y    = buf;   // X==Y aliasing safe: waves only touch their own rows
    float* pred    = (float*)d_out;                     // [N,2]
    float* updated = (float*)d_out + (size_t)N * 2;     // [N,128]

    const dim3 blk(256);
    const int ggrid = (N + 63) / 64;
    const int pgrid = (P + 255) / 256;

    // CSR build for the scatter (int atomics only)
    hipMemsetAsync(counts, 0, (size_t)N * sizeof(int), stream);
    hist_counts<<<pgrid, blk, 0, stream>>>(idx_i, counts, P);
    scan_counts<<<1, 1024, 0, stream>>>(counts, offsets, cursor, N);
    fill_buckets<<<pgrid, blk, 0, stream>>>(idx_i, cursor, bucket, P);

    // xi = act(act(emb @ Wi + bi)); xj = act(act(emb @ Wj + bj))
    gemm_mfma<0, 2, 0><<<ggrid, blk, 0, stream>>>(emb, Wi, bi, nullptr, nullptr, xi, N);
    gemm_mfma<0, 2, 0><<<ggrid, blk, 0, stream>>>(emb, Wj, bj, nullptr, nullptr, xj, N);

    // xi[i] += sum over pairs of (f_ij @ Wg) * xj[idx_j]  (gather, no atomics)
    pair_gather_blk<<<N, blk, 0, stream>>>(f_ij, idx_j, bucket, offsets,
                                           Wg, xj, xi, N);

    // 3 residual blocks: xi = xi + act(act(xi)@w1+b1)@w2 + b2
    for (int k = 0; k < 3; ++k) {
        gemm_mfma<1, 1, 0><<<ggrid, blk, 0, stream>>>(
            xi, res_w1 + (size_t)k * FDIM * FDIM, res_b1 + (size_t)k * FDIM,
            nullptr, nullptr, h, N);
        gemm_mfma<0, 0, 1><<<ggrid, blk, 0, stream>>>(
            h, res_w2 + (size_t)k * FDIM * FDIM, res_b2 + (size_t)k * FDIM,
            xi, nullptr, xi, N);
    }

    // updated = gate*emb + act(xi)@Wv + bv   (written straight to d_out)
    gemm_mfma<1, 0, 2><<<ggrid, blk, 0, stream>>>(xi, Wv, bv, emb, gate, updated, N);

    // output residual block on updated -> y
    gemm_mfma<1, 1, 0><<<ggrid, blk, 0, stream>>>(updated, ores_w1, ores_b1,
                                                  nullptr, nullptr, h, N);
    gemm_mfma<0, 0, 1><<<ggrid, blk, 0, stream>>>(h, ores_w2, ores_b2,
                                                  updated, nullptr, y, N);

    // prediction = y @ Wout + bout
    out_proj<<<(N + 3) / 4, blk, 0, stream>>>(y, Wout, bout, pred, N);
}

// Round 4
// 751.845 us; speedup vs baseline: 2.1868x; 1.2577x over previous
//
#include <hip/hip_runtime.h>
#include <hip/hip_bf16.h>

#define FDIM 128

typedef __attribute__((ext_vector_type(8))) short bf16x8;
typedef __attribute__((ext_vector_type(4))) float f32x4;

__device__ __forceinline__ float sp(float x) {
    // softplus = log(1+exp(x)), numerically stable (== jnp.logaddexp(x,0))
    return fmaxf(x, 0.0f) + log1pf(expf(-fabsf(x)));
}

__device__ __forceinline__ unsigned short bfb(float x) {
    // f32 -> bf16 round-to-nearest-even (inputs are finite; no NaN handling)
    unsigned int u = __float_as_uint(x);
    u += 0x7FFFu + ((u >> 16) & 1u);
    return (unsigned short)(u >> 16);
}

// Y[r][:] = POST( PRE(X[r][:]) @ W + bias ) (+ residual), K = N = 128.
// bf16 MFMA 16x16x32, f32 accumulate. W transposed into LDS (swizzled bf16);
// A-fragments straight from global (each X row read exactly once).
template<int PRE, int POST, int RES>
__global__ __launch_bounds__(256) void gemm_mfma(
    const float* __restrict__ X, const float* __restrict__ W,
    const float* __restrict__ bias, const float* __restrict__ resid,
    const float* __restrict__ gate, float* __restrict__ Y, int nrows)
{
    __shared__ short Wt[FDIM * FDIM];  // 32 KB: Wt[n][k] bf16, XOR-swizzled

    const int t    = threadIdx.x;
    const int lane = t & 63;
    const int wave = t >> 6;

    // ---- stage W^T into LDS as bf16 ----
#pragma unroll
    for (int i = 0; i < 8; ++i) {
        int e  = t + 256 * i;
        int k  = (e >> 5) * 2;
        int n4 = (e & 31) * 4;
        float4 a = *(const float4*)(W + (size_t)k * FDIM + n4);
        float4 b = *(const float4*)(W + (size_t)(k + 1) * FDIM + n4);
        float av[4] = {a.x, a.y, a.z, a.w};
        float bv[4] = {b.x, b.y, b.z, b.w};
#pragma unroll
        for (int j = 0; j < 4; ++j) {
            int n = n4 + j;
            unsigned int pk = (unsigned int)bfb(av[j]) |
                              ((unsigned int)bfb(bv[j]) << 16);
            int byte = n * 256 + k * 2;
            byte ^= (n & 7) << 4;              // bank-conflict swizzle
            *(unsigned int*)((char*)Wt + byte) = pk;
        }
    }

    // ---- A-fragments from global ----
    const int row = blockIdx.x * 64 + wave * 16 + (lane & 15);
    const int kc  = (lane >> 4) * 8;
    const bool rowok = row < nrows;

    bf16x8 afr[4];
#pragma unroll
    for (int ks = 0; ks < 4; ++ks) {
        float4 a = make_float4(0.f, 0.f, 0.f, 0.f);
        float4 b = make_float4(0.f, 0.f, 0.f, 0.f);
        if (rowok) {
            const float* xp = X + (size_t)row * FDIM + ks * 32 + kc;
            a = *(const float4*)xp;
            b = *(const float4*)(xp + 4);
        }
        if (PRE == 1) {
            a.x = sp(a.x); a.y = sp(a.y); a.z = sp(a.z); a.w = sp(a.w);
            b.x = sp(b.x); b.y = sp(b.y); b.z = sp(b.z); b.w = sp(b.w);
        }
        bf16x8 f;
        f[0] = (short)bfb(a.x); f[1] = (short)bfb(a.y);
        f[2] = (short)bfb(a.z); f[3] = (short)bfb(a.w);
        f[4] = (short)bfb(b.x); f[5] = (short)bfb(b.y);
        f[6] = (short)bfb(b.z); f[7] = (short)bfb(b.w);
        afr[ks] = f;
    }

    __syncthreads();

    f32x4 acc[8];
#pragma unroll
    for (int n = 0; n < 8; ++n) acc[n] = (f32x4){0.f, 0.f, 0.f, 0.f};

#pragma unroll
    for (int ks = 0; ks < 4; ++ks) {
#pragma unroll
        for (int n = 0; n < 8; ++n) {
            int nn = n * 16 + (lane & 15);
            int byte = nn * 256 + (ks * 32 + kc) * 2;
            byte ^= (nn & 7) << 4;
            bf16x8 bfr = *(const bf16x8*)((const char*)Wt + byte);
            acc[n] = __builtin_amdgcn_mfma_f32_16x16x32_bf16(afr[ks], bfr, acc[n], 0, 0, 0);
        }
    }

    const int rb = blockIdx.x * 64 + wave * 16 + (lane >> 4) * 4;
#pragma unroll
    for (int n = 0; n < 8; ++n) {
        int col = n * 16 + (lane & 15);
        float bcol = bias[col];
        float gcol = (RES == 2) ? gate[col] : 0.f;
#pragma unroll
        for (int i = 0; i < 4; ++i) {
            int gr = rb + i;
            if (gr >= nrows) continue;
            float o = acc[n][i] + bcol;
            if (POST >= 1) o = sp(o);
            if (POST == 2) o = sp(o);
            if (RES == 1) o += resid[(size_t)gr * FDIM + col];
            if (RES == 2) o = fmaf(gcol, resid[(size_t)gr * FDIM + col], o);
            Y[(size_t)gr * FDIM + col] = o;
        }
    }
}

// ---- CSR build ------------------------------------------------------------

__global__ __launch_bounds__(256) void hist_counts(
    const int* __restrict__ idx_i, int* __restrict__ counts, int npairs)
{
    int p = blockIdx.x * 256 + threadIdx.x;
    if (p < npairs) atomicAdd(&counts[idx_i[p]], 1);
}

// hierarchical coalesced scan: 2048 elements per block
__global__ __launch_bounds__(256) void block_sums(
    const int* __restrict__ counts, int* __restrict__ bsum, int n)
{
    __shared__ int s[256];
    const int t = threadIdx.x;
    const int base = blockIdx.x * 2048;
    int sum = 0;
#pragma unroll
    for (int i = 0; i < 8; ++i) {
        int idx = base + t + 256 * i;
        sum += (idx < n) ? counts[idx] : 0;
    }
    s[t] = sum;
    __syncthreads();
    for (int o = 128; o > 0; o >>= 1) {
        if (t < o) s[t] += s[t + o];
        __syncthreads();
    }
    if (t == 0) bsum[blockIdx.x] = s[0];
}

__global__ void scan_bsums(int* bsum, int nb)
{
    if (threadIdx.x == 0 && blockIdx.x == 0) {
        int run = 0;
        for (int i = 0; i < nb; ++i) { int v = bsum[i]; bsum[i] = run; run += v; }
    }
}

__global__ __launch_bounds__(256) void scan_within(
    const int* __restrict__ counts, const int* __restrict__ bsum,
    int* __restrict__ offsets, int* __restrict__ cursor, int n, int npairs)
{
    __shared__ int ld[2048];
    __shared__ int ps[256];
    const int t = threadIdx.x;
    const int base = blockIdx.x * 2048;
#pragma unroll
    for (int i = 0; i < 8; ++i) {
        int idx = base + t + 256 * i;
        ld[t + 256 * i] = (idx < n) ? counts[idx] : 0;
    }
    __syncthreads();
    int loc[8]; int s = 0;
#pragma unroll
    for (int i = 0; i < 8; ++i) { loc[i] = s; s += ld[t * 8 + i]; }
    ps[t] = s;
    __syncthreads();
    for (int o = 1; o < 256; o <<= 1) {
        int add = (t >= o) ? ps[t - o] : 0;
        __syncthreads();
        ps[t] += add;
        __syncthreads();
    }
    int tbase = bsum[blockIdx.x] + ((t == 0) ? 0 : ps[t - 1]);
#pragma unroll
    for (int i = 0; i < 8; ++i) {
        int idx = base + t * 8 + i;
        if (idx < n) { int v = tbase + loc[i]; offsets[idx] = v; cursor[idx] = v; }
    }
    if (blockIdx.x == gridDim.x - 1 && t == 255) offsets[n] = npairs;
}

__global__ __launch_bounds__(256) void fill_buckets(
    const int* __restrict__ idx_i, const int* __restrict__ idx_j,
    int* __restrict__ cursor, int* __restrict__ bucket,
    int* __restrict__ jperm, int npairs)
{
    int p = blockIdx.x * 256 + threadIdx.x;
    if (p >= npairs) return;
    int pos = atomicAdd(&cursor[idx_i[p]], 1);
    bucket[pos] = p;
    jperm[pos]  = idx_j[p];
}

// One WAVE per atom, breadth-first batches of 16 pairs:
//  - 1 coalesced load of 16 pair ids + 16 j indices (lanes 0..15)
//  - 1 lane-gather float4 load covering all 16 f_ij rows
//  - 16 independent uniform-base xj row loads (readlane -> SGPR base)
//  - compute: per pair 16 readlane broadcasts + FMA into per-lane acc
__global__ __launch_bounds__(256) void pair_gather_wave(
    const float* __restrict__ f_ij, const int* __restrict__ bucket,
    const int* __restrict__ jperm, const int* __restrict__ offsets,
    const float* __restrict__ Wg, const float* __restrict__ xj,
    float* __restrict__ xi, int natoms)
{
    const int lane = threadIdx.x & 63;
    const int wave = threadIdx.x >> 6;
    const int atom = blockIdx.x * 4 + wave;
    if (atom >= natoms) return;

    float2 wreg[16];
#pragma unroll
    for (int r = 0; r < 16; ++r)
        wreg[r] = *(const float2*)(Wg + r * FDIM + lane * 2);

    const int beg = offsets[atom], end = offsets[atom + 1];
    float a0 = 0.f, a1 = 0.f;

    for (int base = beg; base < end; base += 16) {
        int cnt = end - base; if (cnt > 16) cnt = 16;

        // coalesced index loads (lanes 0..15)
        int pv = 0, jv = 0;
        if (lane < cnt) {
            pv = bucket[base + lane];
            jv = jperm[base + lane];
        }

        // f gather: lane l -> pair l>>2, chunk l&3 (one instruction, 16 rows)
        int tq = lane >> 2;
        int pt = __shfl(pv, tq);
        float4 fv = make_float4(0.f, 0.f, 0.f, 0.f);
        if (tq < cnt)
            fv = *(const float4*)(f_ij + (size_t)pt * 16 + (lane & 3) * 4);

        // xj row loads: all independent, uniform SGPR base per pair
        float2 xv[16];
#pragma unroll
        for (int t = 0; t < 16; ++t) {
            xv[t] = make_float2(0.f, 0.f);
            if (t < cnt) {
                int jt = __builtin_amdgcn_readlane(jv, t);
                xv[t] = *(const float2*)(xj + (size_t)jt * FDIM + lane * 2);
            }
        }

        // compute
#pragma unroll
        for (int t = 0; t < 16; ++t) {
            if (t < cnt) {
                float fr[16];
#pragma unroll
                for (int c = 0; c < 4; ++c) {
                    fr[4 * c + 0] = __uint_as_float(__builtin_amdgcn_readlane(__float_as_uint(fv.x), 4 * t + c));
                    fr[4 * c + 1] = __uint_as_float(__builtin_amdgcn_readlane(__float_as_uint(fv.y), 4 * t + c));
                    fr[4 * c + 2] = __uint_as_float(__builtin_amdgcn_readlane(__float_as_uint(fv.z), 4 * t + c));
                    fr[4 * c + 3] = __uint_as_float(__builtin_amdgcn_readlane(__float_as_uint(fv.w), 4 * t + c));
                }
                float gx = 0.f, gy = 0.f;
#pragma unroll
                for (int r = 0; r < 16; ++r) {
                    gx = fmaf(fr[r], wreg[r].x, gx);
                    gy = fmaf(fr[r], wreg[r].y, gy);
                }
                a0 = fmaf(gx, xv[t].x, a0);
                a1 = fmaf(gy, xv[t].y, a1);
            }
        }
    }

    float2* dst = (float2*)(xi + (size_t)atom * FDIM + lane * 2);
    float2 c = *dst;
    c.x += a0; c.y += a1;
    *dst = c;
}

// prediction[r][0..1] = y[r][:] @ Wout + bout ; one wave per row
__global__ __launch_bounds__(256) void out_proj(
    const float* __restrict__ y, const float* __restrict__ Wout,
    const float* __restrict__ bout, float* __restrict__ pred, int nrows)
{
    const int lane = threadIdx.x & 63;
    const int r = blockIdx.x * 4 + (threadIdx.x >> 6);
    if (r >= nrows) return;

    float v0 = y[(size_t)r * FDIM + lane];
    float v1 = y[(size_t)r * FDIM + 64 + lane];
    float2 w0 = ((const float2*)Wout)[lane];
    float2 w1 = ((const float2*)Wout)[lane + 64];
    float a = v0 * w0.x + v1 * w1.x;
    float b = v0 * w0.y + v1 * w1.y;
#pragma unroll
    for (int o = 32; o > 0; o >>= 1) {
        a += __shfl_down(a, o, 64);
        b += __shfl_down(b, o, 64);
    }
    if (lane == 0) {
        pred[(size_t)r * 2 + 0] = a + bout[0];
        pred[(size_t)r * 2 + 1] = b + bout[1];
    }
}

extern "C" void kernel_launch(void* const* d_in, const int* in_sizes, int n_in,
                              void* d_out, int out_size, void* d_ws, size_t ws_size,
                              hipStream_t stream)
{
    const float* emb     = (const float*)d_in[0];
    const float* f_ij    = (const float*)d_in[1];
    const int*   idx_i   = (const int*)d_in[2];
    const int*   idx_j   = (const int*)d_in[3];
    const float* Wi      = (const float*)d_in[4];
    const float* bi      = (const float*)d_in[5];
    const float* Wj      = (const float*)d_in[6];
    const float* bj      = (const float*)d_in[7];
    const float* Wg      = (const float*)d_in[8];
    const float* Wv      = (const float*)d_in[9];
    const float* bv      = (const float*)d_in[10];
    const float* gate    = (const float*)d_in[11];
    const float* res_w1  = (const float*)d_in[12];
    const float* res_b1  = (const float*)d_in[13];
    const float* res_w2  = (const float*)d_in[14];
    const float* res_b2  = (const float*)d_in[15];
    const float* ores_w1 = (const float*)d_in[16];
    const float* ores_b1 = (const float*)d_in[17];
    const float* ores_w2 = (const float*)d_in[18];
    const float* ores_b2 = (const float*)d_in[19];
    const float* Wout    = (const float*)d_in[20];
    const float* bout    = (const float*)d_in[21];

    const int N = in_sizes[0] / FDIM;   // 50000
    const int P = in_sizes[2];          // 800000

    // workspace layout (all rewritten every call; no cross-call state)
    float* xi   = (float*)d_ws;                         // [N,128]
    float* buf  = xi + (size_t)N * FDIM;                // [N,128]: xj -> h -> y
    int*   counts  = (int*)(buf + (size_t)N * FDIM);    // [N]
    int*   offsets = counts + N;                        // [N+1]
    int*   cursor  = offsets + N + 1;                   // [N]
    int*   bucket  = cursor + N;                        // [P]
    int*   jperm   = bucket + P;                        // [P]
    int*   bsum    = jperm + P;                         // [<=64]
    float* xj   = buf;
    float* h    = buf;
    float* y    = buf;
    float* pred    = (float*)d_out;                     // [N,2]
    float* updated = (float*)d_out + (size_t)N * 2;     // [N,128]

    const dim3 blk(256);
    const int ggrid = (N + 63) / 64;
    const int pgrid = (P + 255) / 256;
    const int nb    = (N + 2047) / 2048;

    // CSR build (int atomics only)
    hipMemsetAsync(counts, 0, (size_t)N * sizeof(int), stream);
    hist_counts<<<pgrid, blk, 0, stream>>>(idx_i, counts, P);
    block_sums<<<nb, blk, 0, stream>>>(counts, bsum, N);
    scan_bsums<<<1, 64, 0, stream>>>(bsum, nb);
    scan_within<<<nb, blk, 0, stream>>>(counts, bsum, offsets, cursor, N, P);
    fill_buckets<<<pgrid, blk, 0, stream>>>(idx_i, idx_j, cursor, bucket, jperm, P);

    // xi = act(act(emb @ Wi + bi)); xj = act(act(emb @ Wj + bj))
    gemm_mfma<0, 2, 0><<<ggrid, blk, 0, stream>>>(emb, Wi, bi, nullptr, nullptr, xi, N);
    gemm_mfma<0, 2, 0><<<ggrid, blk, 0, stream>>>(emb, Wj, bj, nullptr, nullptr, xj, N);

    // xi[i] += sum over pairs of (f_ij @ Wg) * xj[idx_j]
    pair_gather_wave<<<(N + 3) / 4, blk, 0, stream>>>(f_ij, bucket, jperm, offsets,
                                                      Wg, xj, xi, N);

    // 3 residual blocks
    for (int k = 0; k < 3; ++k) {
        gemm_mfma<1, 1, 0><<<ggrid, blk, 0, stream>>>(
            xi, res_w1 + (size_t)k * FDIM * FDIM, res_b1 + (size_t)k * FDIM,
            nullptr, nullptr, h, N);
        gemm_mfma<0, 0, 1><<<ggrid, blk, 0, stream>>>(
            h, res_w2 + (size_t)k * FDIM * FDIM, res_b2 + (size_t)k * FDIM,
            xi, nullptr, xi, N);
    }

    // updated = gate*emb + act(xi)@Wv + bv
    gemm_mfma<1, 0, 2><<<ggrid, blk, 0, stream>>>(xi, Wv, bv, emb, gate, updated, N);

    // output residual block
    gemm_mfma<1, 1, 0><<<ggrid, blk, 0, stream>>>(updated, ores_w1, ores_b1,
                                                  nullptr, nullptr, h, N);
    gemm_mfma<0, 0, 1><<<ggrid, blk, 0, stream>>>(h, ores_w2, ores_b2,
                                                  updated, nullptr, y, N);

    // prediction = y @ Wout + bout
    out_proj<<<(N + 3) / 4, blk, 0, stream>>>(y, Wout, bout, pred, N);
}